// Round 7
// baseline (256.843 us; speedup 1.0000x reference)
//
#include <hip/hip_runtime.h>
#include <hip/hip_bf16.h>
#include <math.h>

#define C_DIM 1024
#define CR    256
#define A_N   10
#define NANCH 3
#define B_N   2
#define HW_N  4096
#define NTOK  (B_N*HW_N)   // 8192
#define KG2   (A_N*CR)     // 2560
// prep dynamic LDS: f32 tile [16][1025] + st2 128 + mr 32 floats
#define PREP_LDS ((16*1025 + 128 + 32) * 4)

typedef unsigned short ushort_t;
typedef unsigned int uint_t;
typedef __attribute__((ext_vector_type(4))) float f32x4;
typedef __attribute__((ext_vector_type(8))) short bf16x8;

__device__ __forceinline__ ushort_t f2bf(float x) {
    __hip_bfloat16 h = __float2bfloat16(x);
    return *reinterpret_cast<ushort_t*>(&h);
}
__device__ __forceinline__ float bf2f(ushort_t u) {
    return __uint_as_float(((unsigned)u) << 16);
}

// tanh-form GELU via sigmoid identity; |err| < ~1e-3 (below bf16 rounding)
__device__ __forceinline__ float fast_gelu(float x) {
    float t = x * x;
    float u = x * (-1.5957691216f - 0.0713548163f * t);
    float e = __expf(u);
    return x * __frcp_rn(1.0f + e);
}

// ================= consolidated prep kernel (no memset needed) =================
// block 0          : wsel single-block: per-thread counts -> LDS prefix scan ->
//                    placement. cnt written directly (no global atomics/zeroing).
// blocks [1,513)   : LayerNorm, 16 tokens/block: feat read ONCE into a 64.7 KB
//                    f32 LDS tile during the stats pass; normalize from LDS.
// blocks [513,1153): w1t[a][d][c] = bf16(ln_scale[a][c]*w1[a][c][d]) + bias1
//                    partial -> bias1p[a][c-chunk][d] (non-atomic, summed in gemm1)
__global__ __launch_bounds__(256) void prep_all(
    const float* __restrict__ w1,
    const float* __restrict__ ln_s, const float* __restrict__ ln_b,
    const float* __restrict__ feat, const float* __restrict__ ar,
    ushort_t* __restrict__ w1t,
    float* __restrict__ bias1p, int* __restrict__ cnt,
    int* __restrict__ tokw, int* __restrict__ tokmap,
    ushort_t* __restrict__ normG) {
    extern __shared__ __align__(16) char smem[];
    int id = blockIdx.x, tid = threadIdx.x;
    int lo = tid & 63, hi = tid >> 6;

    if (id == 0) {                        // ---- wsel: classify + compact, 1 block ----
        int* shc = (int*)smem;            // [10][256] per-thread counts
        int* shb = shc + A_N * 256;       // [10][256] exclusive bases
        const float THR[9] = {1.0f/9.0f, 1.0f/7.0f, 0.2f, 1.0f/3.0f, 1.0f, 3.0f, 5.0f, 7.0f, 9.0f};
        int cl[A_N];
        #pragma unroll
        for (int a = 0; a < A_N; a++) cl[a] = 0;
        // phase 1: count unique adapters per token (thread owns t = it*256+tid)
        for (int it = 0; it < 32; it++) {
            int t = it * 256 + tid;
            int b = t >> 12, p = t & (HW_N - 1);
            int idxs[NANCH];
            #pragma unroll
            for (int na = 0; na < NANCH; na++) {
                float v = ar[(size_t)b * NANCH * HW_N + na * HW_N + p];
                int idx = 0;
                #pragma unroll
                for (int i = 0; i < 9; i++) idx += (v > THR[i]) ? 1 : 0;
                idxs[na] = idx;
            }
            #pragma unroll
            for (int j = 0; j < NANCH; j++) {
                bool first = true;
                #pragma unroll
                for (int k = 0; k < j; k++) first = first && (idxs[k] != idxs[j]);
                if (first) {
                    #pragma unroll
                    for (int a = 0; a < A_N; a++) cl[a] += (idxs[j] == a) ? 1 : 0;
                }
            }
        }
        #pragma unroll
        for (int a = 0; a < A_N; a++) shc[a * 256 + tid] = cl[a];
        __syncthreads();
        if (tid < A_N) {                  // serial 256-scan per adapter
            int run = 0;
            for (int i = 0; i < 256; i++) {
                int v = shc[tid * 256 + i];
                shb[tid * 256 + i] = run;
                run += v;
            }
            cnt[tid] = run;
        }
        __syncthreads();
        // phase 2: re-classify and place at base + running offset
        int off[A_N];
        #pragma unroll
        for (int a = 0; a < A_N; a++) off[a] = 0;
        for (int it = 0; it < 32; it++) {
            int t = it * 256 + tid;
            int b = t >> 12, p = t & (HW_N - 1);
            int idxs[NANCH];
            #pragma unroll
            for (int na = 0; na < NANCH; na++) {
                float v = ar[(size_t)b * NANCH * HW_N + na * HW_N + p];
                int idx = 0;
                #pragma unroll
                for (int i = 0; i < 9; i++) idx += (v > THR[i]) ? 1 : 0;
                idxs[na] = idx;
            }
            int myA[NANCH], myC[NANCH], nmine = 0;
            #pragma unroll
            for (int j = 0; j < NANCH; j++) {
                bool first = true; int c3 = 0;
                #pragma unroll
                for (int k = 0; k < NANCH; k++) {
                    if (idxs[k] == idxs[j]) { c3++; if (k < j) first = false; }
                }
                if (first) { myA[nmine] = idxs[j]; myC[nmine] = c3; nmine++; }
            }
            #pragma unroll
            for (int i = 0; i < NANCH; i++) {
                if (i < nmine) {
                    int aj = myA[i], pos = 0;
                    #pragma unroll
                    for (int a = 0; a < A_N; a++) {
                        if (aj == a) { pos = shb[a * 256 + tid] + off[a]; off[a]++; }
                    }
                    tokw[aj * NTOK + pos] = t;
                    tokmap[t * 3 + i] = pos | (aj << 13) | (myC[i] << 17);
                } else {
                    tokmap[t * 3 + i] = 0;    // weight 0 -> ignored
                }
            }
        }
    } else if (id < 513) {                // ---- LN: single feat read via LDS tile ----
        int lnid = id - 1;
        int b = lnid >> 8, p0 = (lnid & 255) * 16;
        const float* fb = feat + (size_t)b * C_DIM * HW_N + p0;
        float* tile = (float*)smem;       // [16][1025] f32 (pitch 1025: bank=(p+c)%32)
        float* st2 = tile + 16 * 1025;    // [4 waves][16 tok][2]
        float* mrr = st2 + 128;           // [2][16] mean / rstd
        // pass 1: load f32x4 (4 tokens) per c-row, accumulate stats, stash in LDS
        int pg = tid & 3, crr = tid >> 2;  // pg: token quad; crr: c-row stride 64
        float s[4] = {0.f, 0.f, 0.f, 0.f}, q[4] = {0.f, 0.f, 0.f, 0.f};
        for (int c = crr; c < C_DIM; c += 64) {
            f32x4 v = *(const f32x4*)(fb + (size_t)c * HW_N + pg * 4);
            #pragma unroll
            for (int k = 0; k < 4; k++) {
                s[k] += v[k]; q[k] += v[k] * v[k];
                tile[(pg * 4 + k) * 1025 + c] = v[k];
            }
        }
        // reduce over crr: lane bits 2-5 hold crr-low -> 4 shfl_xor steps
        int w = tid >> 6, lane = tid & 63;
        #pragma unroll
        for (int k = 0; k < 4; k++) {
            float sv = s[k], qv = q[k];
            #pragma unroll
            for (int m = 4; m <= 32; m <<= 1) {
                sv += __shfl_xor(sv, m);
                qv += __shfl_xor(qv, m);
            }
            if (lane < 4) {               // lane == pg
                st2[((w * 16) + (lane * 4 + k)) * 2 + 0] = sv;
                st2[((w * 16) + (lane * 4 + k)) * 2 + 1] = qv;
            }
        }
        __syncthreads();
        if (tid < 16) {
            float S = 0.f, Q = 0.f;
            #pragma unroll
            for (int ww = 0; ww < 4; ww++) {
                S += st2[(ww * 16 + tid) * 2 + 0];
                Q += st2[(ww * 16 + tid) * 2 + 1];
            }
            float m = S * (1.f / C_DIM);
            float qq = Q * (1.f / C_DIM);
            mrr[tid] = m;
            mrr[16 + tid] = rsqrtf(qq - m * m + 1e-5f);
        }
        __syncthreads();
        // pass 2 (LDS only): normalize + packed bf16x2 write, token-major
        #pragma unroll
        for (int i = 0; i < 4; i++) {
            int p_l = i * 4 + hi;
            float m = mrr[p_l], r = mrr[16 + p_l];
            size_t t = (size_t)(b * HW_N + p0 + p_l);
            #pragma unroll
            for (int cc = 0; cc < 8; cc++) {
                int c = cc * 128 + lo * 2;
                float x0 = tile[p_l * 1025 + c];
                float x1 = tile[p_l * 1025 + c + 1];
                uint_t u = (uint_t)f2bf((x0 - m) * r) | ((uint_t)f2bf((x1 - m) * r) << 16);
                *(uint_t*)(normG + t * C_DIM + c) = u;
            }
        }
    } else {                              // ---- prep_w1t + bias1 partial ----
        int idw = id - 513;
        int d0 = (idw & 3) * 64, c0 = ((idw >> 2) & 15) * 64, a = idw >> 6;
        float (*lds)[65] = (float(*)[65])smem;     // [64][65]
        float* bb = (float*)smem + 64 * 65;        // [4][64]
        #pragma unroll
        for (int i = 0; i < 16; i++) {
            int c_l = i * 4 + hi;
            lds[c_l][lo] = w1[((size_t)a * C_DIM + c0 + c_l) * CR + d0 + lo];  // raw
        }
        __syncthreads();
        // bias partial: thread owns d=lo, sums 16 c's
        {
            float s = 0.f;
            #pragma unroll
            for (int cc = 0; cc < 16; cc++) {
                int c = hi * 16 + cc;
                s += lds[c][lo] * ln_b[a * C_DIM + c0 + c];
            }
            bb[hi * 64 + lo] = s;
        }
        // scaled transpose store
        float sc = ln_s[a * C_DIM + c0 + lo];
        #pragma unroll
        for (int i = 0; i < 16; i++) {
            int d_l = i * 4 + hi;
            w1t[((size_t)a * CR + d0 + d_l) * C_DIM + c0 + lo] = f2bf(lds[lo][d_l] * sc);
        }
        __syncthreads();
        if (hi == 0)                      // unique (a, c-chunk, d) slot: no atomic
            bias1p[((size_t)a * 16 + (c0 >> 6)) * 256 + d0 + lo] =
                bb[0 * 64 + lo] + bb[1 * 64 + lo] + bb[2 * 64 + lo] + bb[3 * 64 + lo];
    }
}

// ========= GEMM1 (BK=128, 64 MFMA/wave per barrier) + w2t prep in one dispatch =========
// blocks [0,1280)    : Hc[base_a+i][d] = gelu(norm[tok_i] @ w1'[a] + bias[a])
//                      bias = sum of 16 bias1p partials (hoisted, hidden by K-loop)
// blocks [1280,1920) : w2t[c][a*CR+d] = bf16(w2 transposed) -- only consumed by
//                      gemm2w, so it back-fills CUs during gemm1's tail.
__global__ __launch_bounds__(256) void gemm1c(const ushort_t* __restrict__ normG,
                                              const ushort_t* __restrict__ w1t,
                                              const float* __restrict__ bias1p,
                                              const int* __restrict__ tokw,
                                              const int* __restrict__ cnt,
                                              ushort_t* __restrict__ Hc,
                                              const float* __restrict__ w2,
                                              ushort_t* __restrict__ w2t) {
    __shared__ __align__(16) ushort_t As[2][128 * 64];   // 32 KB (two k-halves)
    __shared__ __align__(16) ushort_t Bs[2][128 * 64];   // 32 KB
    int id = blockIdx.x, tid = threadIdx.x;

    if (id >= 1280) {                     // ---- w2t prep (reuses As as f32 tile) ----
        int idw = id - 1280;
        int k0 = (idw % 40) * 64, c0 = (idw / 40) * 64;
        int lo = tid & 63, hi = tid >> 6;
        float (*lds)[65] = (float(*)[65])As;   // 16.6 KB < 32 KB
        #pragma unroll
        for (int i = 0; i < 16; i++) {
            int k_l = i * 4 + hi;
            lds[k_l][lo] = w2[((size_t)k0 + k_l) * C_DIM + c0 + lo];
        }
        __syncthreads();
        #pragma unroll
        for (int i = 0; i < 16; i++) {
            int c_l = i * 4 + hi;
            w2t[((size_t)c0 + c_l) * KG2 + k0 + lo] = f2bf(lds[lo][c_l]);
        }
        return;
    }

    int a = id >> 7;
    int rem = id & 127;
    int m0 = (rem >> 1) * 128;
    int n0 = (rem & 1) * 128;
    int mcount = cnt[a];
    if (m0 >= mcount) return;
    int base = 0;
    for (int a2 = 0; a2 < a; a2++) base += cnt[a2];

    const int lane = tid & 63, w = tid >> 6;
    const int wr = w >> 1, wc = w & 1;
    const int lrow = lane & 15, quad = lane >> 4, swzr = lrow & 7;
    const int lrow8 = lane >> 3;
    const int scol = ((lane & 7) ^ lrow8) * 8;
    const int srowl = w * 32 + lrow8;

    const ushort_t* ap[4];
    const ushort_t* bp[4];
    #pragma unroll
    for (int i = 0; i < 4; i++) {
        int rt = tokw[a * NTOK + m0 + srowl + i * 8] & (NTOK - 1);
        ap[i] = normG + (size_t)rt * C_DIM + scol;
        bp[i] = w1t + ((size_t)a * CR + n0 + srowl + i * 8) * C_DIM + scol;
    }

    // hoisted: 16-partial bias sum overlaps the K loop
    float bi[4] = {0.f, 0.f, 0.f, 0.f};
    #pragma unroll
    for (int nt = 0; nt < 4; nt++) {
        int col = n0 + wc * 64 + nt * 16 + lrow;
        #pragma unroll
        for (int cb = 0; cb < 16; cb++)
            bi[nt] += bias1p[((size_t)a * 16 + cb) * 256 + col];
    }

    f32x4 acc[4][4];
    #pragma unroll
    for (int i = 0; i < 4; i++)
        #pragma unroll
        for (int j = 0; j < 4; j++)
            #pragma unroll
            for (int e = 0; e < 4; e++) acc[i][j][e] = 0.f;

    for (int k0 = 0; k0 < C_DIM; k0 += 128) {
        __syncthreads();                       // prior phase's reads done
        #pragma unroll
        for (int h = 0; h < 2; h++) {
            int kk = k0 + h * 64;
            #pragma unroll
            for (int i = 0; i < 4; i++) {
                __builtin_amdgcn_global_load_lds(
                    (__attribute__((address_space(1))) void*)(ap[i] + kk),
                    (__attribute__((address_space(3))) void*)(&As[h][(w * 32 + i * 8) * 64]),
                    16, 0, 0);
                __builtin_amdgcn_global_load_lds(
                    (__attribute__((address_space(1))) void*)(bp[i] + kk),
                    (__attribute__((address_space(3))) void*)(&Bs[h][(w * 32 + i * 8) * 64]),
                    16, 0, 0);
            }
        }
        __syncthreads();                       // data ready (drains vmcnt once per 128-K)
        #pragma unroll
        for (int h = 0; h < 2; h++)
            #pragma unroll
            for (int ks = 0; ks < 2; ks++) {
                const int cidx = ((ks * 4 + quad) ^ swzr) * 8;
                bf16x8 af[4], bfr[4];
                #pragma unroll
                for (int mt = 0; mt < 4; mt++)
                    af[mt] = *(const bf16x8*)(&As[h][(wr * 64 + mt * 16 + lrow) * 64 + cidx]);
                #pragma unroll
                for (int nt = 0; nt < 4; nt++)
                    bfr[nt] = *(const bf16x8*)(&Bs[h][(wc * 64 + nt * 16 + lrow) * 64 + cidx]);
                #pragma unroll
                for (int mt = 0; mt < 4; mt++)
                    #pragma unroll
                    for (int nt = 0; nt < 4; nt++)
                        acc[mt][nt] = __builtin_amdgcn_mfma_f32_16x16x32_bf16(af[mt], bfr[nt], acc[mt][nt], 0, 0, 0);
            }
    }

    #pragma unroll
    for (int mt = 0; mt < 4; mt++)
        #pragma unroll
        for (int r = 0; r < 4; r++) {
            int i_row = m0 + wr * 64 + mt * 16 + quad * 4 + r;
            bool live = i_row < mcount;
            #pragma unroll
            for (int nt = 0; nt < 4; nt++) {
                int col = n0 + wc * 64 + nt * 16 + lrow;
                float v = acc[mt][nt][r] + bi[nt];
                if (live)
                    Hc[(size_t)(base + i_row) * CR + col] = f2bf(fast_gelu(v));
            }
        }
}

// GEMM2 wide (512 thr, 8 waves 2x4): O[base_a+i][n0..n0+256) = Hc_a[i] @ w2t[a]
// 128x256 tile, K=256. 48 KB LDS -> 3 blocks/CU co-resident.
__global__ __launch_bounds__(512) void gemm2w(const ushort_t* __restrict__ Hc,
                                              const ushort_t* __restrict__ w2t,
                                              const int* __restrict__ cnt,
                                              ushort_t* __restrict__ O) {
    int a = blockIdx.z;
    int mcount = cnt[a];
    int m0 = blockIdx.y * 128;
    if (m0 >= mcount) return;
    int n0 = blockIdx.x * 256;
    int base = 0;
    for (int a2 = 0; a2 < a; a2++) base += cnt[a2];

    __shared__ __align__(16) ushort_t As[128 * 64];   // 16 KB
    __shared__ __align__(16) ushort_t Bs[256 * 64];   // 32 KB

    const int tid = threadIdx.x;
    const int lane = tid & 63, w = tid >> 6;
    const int wr = w >> 2, wc = w & 3;          // 2x4 wave grid
    const int lrow = lane & 15, quad = lane >> 4, swzr = lrow & 7;
    const int srow = tid >> 3;                  // 0..63 staging row within group
    const int slotswz = ((tid & 7) ^ (srow & 7)) * 8;  // pre-swizzled k8 slot

    const ushort_t* ap[2];
    #pragma unroll
    for (int i = 0; i < 2; i++)
        ap[i] = Hc + (size_t)(base + m0 + i * 64 + srow) * CR + slotswz;
    const ushort_t* bp[4];
    #pragma unroll
    for (int i = 0; i < 4; i++)
        bp[i] = w2t + (size_t)(n0 + i * 64 + srow) * KG2 + (size_t)a * CR + slotswz;

    f32x4 acc[4][4];
    #pragma unroll
    for (int i = 0; i < 4; i++)
        #pragma unroll
        for (int j = 0; j < 4; j++)
            #pragma unroll
            for (int e = 0; e < 4; e++) acc[i][j][e] = 0.f;

    for (int k0 = 0; k0 < CR; k0 += 64) {
        __syncthreads();
        #pragma unroll
        for (int i = 0; i < 2; i++)
            __builtin_amdgcn_global_load_lds(
                (__attribute__((address_space(1))) void*)(ap[i] + k0),
                (__attribute__((address_space(3))) void*)(As + i * 4096 + w * 512),
                16, 0, 0);
        #pragma unroll
        for (int i = 0; i < 4; i++)
            __builtin_amdgcn_global_load_lds(
                (__attribute__((address_space(1))) void*)(bp[i] + k0),
                (__attribute__((address_space(3))) void*)(Bs + i * 4096 + w * 512),
                16, 0, 0);
        __syncthreads();
        #pragma unroll
        for (int ks = 0; ks < 2; ks++) {
            const int cidx = ((ks * 4 + quad) ^ swzr) * 8;
            bf16x8 af[4], bfr[4];
            #pragma unroll
            for (int mt = 0; mt < 4; mt++)
                af[mt] = *(const bf16x8*)(As + (wr * 64 + mt * 16 + lrow) * 64 + cidx);
            #pragma unroll
            for (int nt = 0; nt < 4; nt++)
                bfr[nt] = *(const bf16x8*)(Bs + (wc * 64 + nt * 16 + lrow) * 64 + cidx);
            #pragma unroll
            for (int mt = 0; mt < 4; mt++)
                #pragma unroll
                for (int nt = 0; nt < 4; nt++)
                    acc[mt][nt] = __builtin_amdgcn_mfma_f32_16x16x32_bf16(af[mt], bfr[nt], acc[mt][nt], 0, 0, 0);
        }
    }

    #pragma unroll
    for (int mt = 0; mt < 4; mt++)
        #pragma unroll
        for (int r = 0; r < 4; r++) {
            int i_row = m0 + wr * 64 + mt * 16 + quad * 4 + r;
            bool live = i_row < mcount;
            #pragma unroll
            for (int nt = 0; nt < 4; nt++) {
                int col = n0 + wc * 64 + nt * 16 + lrow;
                if (live)
                    O[(size_t)(base + i_row) * C_DIM + col] = f2bf(acc[mt][nt][r]);
            }
        }
}

// final gather: out[b][c][p] = feat + sum_j w_j * O[gpos_j(t)][c]
// 64p x 128c tile; uint (2xbf16) gathers halve the latency-bound gather
// instruction count. 129-pitch LDS keeps the transposed read conflict-free.
__global__ __launch_bounds__(256) void finalk2(const ushort_t* __restrict__ O,
                                               const int* __restrict__ tokmap,
                                               const int* __restrict__ cnt,
                                               const float* __restrict__ feat,
                                               float* __restrict__ out) {
    int p0 = blockIdx.x * 64, c0 = blockIdx.y * 128, b = blockIdx.z;
    __shared__ float lds[64][129];
    __shared__ int pbase[A_N];
    int tid = threadIdx.x, lo = tid & 63, hi = tid >> 6;
    if (tid < A_N) {
        int s = 0;
        for (int k = 0; k < tid; k++) s += cnt[k];
        pbase[tid] = s;
    }
    __syncthreads();
    #pragma unroll
    for (int i = 0; i < 16; i++) {
        int tl = i * 4 + hi;
        int t = b * HW_N + p0 + tl;
        float v0 = 0.f, v1 = 0.f;
        #pragma unroll
        for (int j = 0; j < 3; j++) {
            int e = tokmap[t * 3 + j];
            float wv = (float)(e >> 17) * (1.0f / 3.0f);
            int a2 = (e >> 13) & 15;
            int row = pbase[a2] + (e & 8191);
            uint_t u = *(const uint_t*)(O + (size_t)row * C_DIM + c0 + lo * 2);
            v0 += wv * bf2f((ushort_t)(u & 0xffffu));
            v1 += wv * bf2f((ushort_t)(u >> 16));
        }
        lds[tl][lo * 2] = v0;
        lds[tl][lo * 2 + 1] = v1;
    }
    __syncthreads();
    #pragma unroll
    for (int i = 0; i < 32; i++) {
        int c_l = i * 4 + hi;
        size_t o = ((size_t)b * C_DIM + c0 + c_l) * HW_N + p0 + lo;
        out[o] = lds[lo][c_l] + feat[o];
    }
}

// ---------------- launch ----------------
extern "C" void kernel_launch(void* const* d_in, const int* in_sizes, int n_in,
                              void* d_out, int out_size, void* d_ws, size_t ws_size,
                              hipStream_t stream) {
    (void)in_sizes; (void)n_in; (void)out_size; (void)ws_size;
    const float* feat = (const float*)d_in[0];
    const float* ar   = (const float*)d_in[1];
    const float* ln_s = (const float*)d_in[2];
    const float* ln_b = (const float*)d_in[3];
    const float* w1   = (const float*)d_in[4];
    const float* w2   = (const float*)d_in[5];
    float* out = (float*)d_out;
    char* ws = (char*)d_ws;

    // allow >64 KB dynamic LDS for prep_all's LN tile
    (void)hipFuncSetAttribute((const void*)prep_all,
                              hipFuncAttributeMaxDynamicSharedMemorySize,
                              PREP_LDS);

    // ---- workspace (NO zero-init required anywhere) ----
    float*    bias1p = (float*)(ws + 0);          // 10*16*256*4 = 163,840
    int*      cnt    = (int*)(ws + 163840);       // 40 (pad to 164,096)
    int*      tokmap = (int*)(ws + 164096);       // 98,304   -> 262,400
    int*      tokw   = (int*)(ws + 262400);       // 327,680  -> 590,080
    ushort_t* w1t    = (ushort_t*)(ws + 590080);  // 5,242,880 -> 5,832,960
    ushort_t* w2t    = (ushort_t*)(ws + 5832960); // 5,242,880 -> 11,075,840
    ushort_t* normG  = (ushort_t*)(ws + 11075840);// 16,777,216 -> 27,853,056
    ushort_t* Hc     = (ushort_t*)(ws + 27853056);// (24576+128)*256*2 = 12,648,448 -> 40,501,504
    ushort_t* O      = (ushort_t*)(ws + 40501504);// 24576*1024*2 = 50,331,648 -> 90,833,152

    dim3 blk(256);
    prep_all<<<dim3(1153), blk, PREP_LDS, stream>>>(w1, ln_s, ln_b, feat, ar,
                                                    w1t, bias1p, cnt, tokw, tokmap, normG);
    gemm1c<<<dim3(1920), blk, 0, stream>>>(normG, w1t, bias1p, tokw, cnt, Hc, w2, w2t);
    gemm2w<<<dim3(4, 64, A_N), dim3(512), 0, stream>>>(Hc, w2t, cnt, O);
    finalk2<<<dim3(64, 8, B_N), blk, 0, stream>>>(O, tokmap, cnt, feat, out);
}

// Round 8
// 175.597 us; speedup vs baseline: 1.4627x; 1.4627x over previous
//
#include <hip/hip_runtime.h>
#include <hip/hip_bf16.h>
#include <math.h>

#define C_DIM 1024
#define CR    256
#define A_N   10
#define NANCH 3
#define B_N   2
#define HW_N  4096
#define NTOK  (B_N*HW_N)   // 8192
#define KG2   (A_N*CR)     // 2560
#define FIN_LDS (64 * 258 * 4)   // 66,048 B f32 staging tile -> 2 blocks/CU

typedef unsigned short ushort_t;
typedef unsigned int uint_t;
typedef __attribute__((ext_vector_type(2))) unsigned int uint32x2;
typedef __attribute__((ext_vector_type(4))) float f32x4;
typedef __attribute__((ext_vector_type(8))) short bf16x8;

__device__ __forceinline__ ushort_t f2bf(float x) {
    __hip_bfloat16 h = __float2bfloat16(x);
    return *reinterpret_cast<ushort_t*>(&h);
}
__device__ __forceinline__ float bf2f(ushort_t u) {
    return __uint_as_float(((unsigned)u) << 16);
}

// tanh-form GELU via sigmoid identity; |err| < ~1e-3 (below bf16 rounding)
__device__ __forceinline__ float fast_gelu(float x) {
    float t = x * x;
    float u = x * (-1.5957691216f - 0.0713548163f * t);
    float e = __expf(u);
    return x * __frcp_rn(1.0f + e);
}

// ================= consolidated prep kernel (round-6 proven structure) =================
// blocks [0,256)    : fused LayerNorm, 32 tokens/block (1 block per CU)
// blocks [256,288)  : wsel compaction (hierarchical LDS counts) + tokmap
//                     NOTE: block-sequential order is a contract with gemm1's
//                     gather locality -- do not reorder (round-7 lesson).
// blocks [288,928)  : w1t prep + bias1 partial (atomic into zeroed bias1)
// blocks [928,1568) : w2t transposed prep
__global__ __launch_bounds__(256) void prep_all(
    const float* __restrict__ w1, const float* __restrict__ w2,
    const float* __restrict__ ln_s, const float* __restrict__ ln_b,
    const float* __restrict__ feat, const float* __restrict__ ar,
    ushort_t* __restrict__ w1t, ushort_t* __restrict__ w2t,
    float* __restrict__ bias1, int* __restrict__ cnt,
    int* __restrict__ tokw, int* __restrict__ tokmap,
    ushort_t* __restrict__ normG) {
    __shared__ float lds[64][65];
    __shared__ float bb[4][64];
    __shared__ float st[8][256];      // LN partial sums: st[k][tid], st[4+k][tid]
    __shared__ float mr[2][64];       // LN mean / rstd per token
    __shared__ int lcnt[A_N], lpos[A_N], gbase[A_N];
    int id = blockIdx.x, tid = threadIdx.x;
    int lo = tid & 63, hi = tid >> 6;

    if (id < 256) {                       // ---- fused LN (stats + normalize) ----
        int b = id >> 7, p0 = (id & 127) * 32;
        const float* fb = feat + (size_t)b * C_DIM * HW_N + p0;
        // pass 1: block-local mean/var over 32 tokens x 1024 channels.
        int pg = tid & 7, cr = tid >> 3;
        float s[4] = {0.f, 0.f, 0.f, 0.f}, q[4] = {0.f, 0.f, 0.f, 0.f};
        #pragma unroll 4
        for (int c = cr; c < C_DIM; c += 32) {
            f32x4 v = *(const f32x4*)(fb + (size_t)c * HW_N + pg * 4);
            #pragma unroll
            for (int k = 0; k < 4; k++) { s[k] += v[k]; q[k] += v[k] * v[k]; }
        }
        #pragma unroll
        for (int k = 0; k < 4; k++) { st[k][tid] = s[k]; st[4 + k][tid] = q[k]; }
        __syncthreads();
        if (tid < 32) {                   // token tt = tid: pg = tt>>2, k = tt&3
            int pgr = tid >> 2, k = tid & 3;
            float S = 0.f, Q = 0.f;
            #pragma unroll
            for (int c2 = 0; c2 < 32; c2++) {
                S += st[k][c2 * 8 + pgr];
                Q += st[4 + k][c2 * 8 + pgr];
            }
            float m = S * (1.f / C_DIM);
            float qq = Q * (1.f / C_DIM);
            mr[0][tid] = m;
            mr[1][tid] = rsqrtf(qq - m * m + 1e-5f);
        }
        // pass 2: re-read (L2/L3-hot), LDS-transpose (odd pitch 33 -> no bank
        // conflicts on the transposed read), write normG token-major
        float (*l33)[33] = (float(*)[33])lds;
        for (int cc = 0; cc < 16; cc++) {
            int c0 = cc * 64;
            __syncthreads();
            #pragma unroll
            for (int rep = 0; rep < 2; rep++) {
                int c_l = rep * 32 + (tid >> 3), pj = tid & 7;
                f32x4 v = *(const f32x4*)(fb + (size_t)(c0 + c_l) * HW_N + pj * 4);
                #pragma unroll
                for (int k = 0; k < 4; k++) l33[c_l][pj * 4 + k] = v[k];
            }
            __syncthreads();
            #pragma unroll
            for (int i = 0; i < 8; i++) {
                int p_l = i * 4 + hi;
                normG[((size_t)(b * HW_N + p0 + p_l)) * C_DIM + c0 + lo] =
                    f2bf((l33[lo][p_l] - mr[0][p_l]) * mr[1][p_l]);
            }
        }
    } else if (id < 288) {                // ---- wsel compaction + tokmap ----
        if (tid < A_N) { lcnt[tid] = 0; lpos[tid] = 0; }
        __syncthreads();
        int t = (id - 256) * 256 + tid;   // < 8192
        int b = t >> 12, p = t & (HW_N - 1);
        const float THR[9] = {1.0f/9.0f, 1.0f/7.0f, 0.2f, 1.0f/3.0f, 1.0f, 3.0f, 5.0f, 7.0f, 9.0f};
        int idxs[NANCH];
        #pragma unroll
        for (int na = 0; na < NANCH; na++) {
            float v = ar[(size_t)b * NANCH * HW_N + na * HW_N + p];
            int idx = 0;
            #pragma unroll
            for (int i = 0; i < 9; i++) idx += (v > THR[i]) ? 1 : 0;
            idxs[na] = idx;
        }
        int myA[NANCH], myC[NANCH], nmine = 0;
        #pragma unroll
        for (int j = 0; j < NANCH; j++) {
            bool first = true; int c3 = 0;
            #pragma unroll
            for (int k = 0; k < NANCH; k++) {
                if (idxs[k] == idxs[j]) { c3++; if (k < j) first = false; }
            }
            if (first) {
                myA[nmine] = idxs[j];
                myC[nmine] = c3;
                nmine++;
                atomicAdd(&lcnt[idxs[j]], 1);
            }
        }
        __syncthreads();
        if (tid < A_N) gbase[tid] = atomicAdd(&cnt[tid], lcnt[tid]);
        __syncthreads();
        for (int i = 0; i < NANCH; i++) {
            if (i < nmine) {
                int a2 = myA[i];
                int slot = atomicAdd(&lpos[a2], 1);
                int pos = gbase[a2] + slot;                 // global pos in adapter list
                tokw[a2 * NTOK + pos] = t;                  // row gather for gemm1c
                tokmap[t * 3 + i] = pos | (a2 << 13) | (myC[i] << 17);
            } else {
                tokmap[t * 3 + i] = 0;                      // weight 0 -> ignored
            }
        }
    } else if (id < 928) {                // ---- prep_w1t + bias1 ----
        int idw = id - 288;
        int d0 = (idw & 3) * 64, c0 = ((idw >> 2) & 15) * 64, a = idw >> 6;
        #pragma unroll
        for (int i = 0; i < 16; i++) {
            int c_l = i * 4 + hi;
            lds[c_l][lo] = w1[((size_t)a * C_DIM + c0 + c_l) * CR + d0 + lo];  // raw
        }
        __syncthreads();
        // bias partial: thread owns d=lo, sums 16 c's
        {
            float s = 0.f;
            #pragma unroll
            for (int cc = 0; cc < 16; cc++) {
                int c = hi * 16 + cc;
                s += lds[c][lo] * ln_b[a * C_DIM + c0 + c];
            }
            bb[hi][lo] = s;
        }
        // scaled transpose store
        float sc = ln_s[a * C_DIM + c0 + lo];
        #pragma unroll
        for (int i = 0; i < 16; i++) {
            int d_l = i * 4 + hi;
            w1t[((size_t)a * CR + d0 + d_l) * C_DIM + c0 + lo] = f2bf(lds[lo][d_l] * sc);
        }
        __syncthreads();
        if (hi == 0)
            atomicAdd(&bias1[a * CR + d0 + lo], bb[0][lo] + bb[1][lo] + bb[2][lo] + bb[3][lo]);
    } else {                              // ---- prep_w2t ----
        int idw = id - 928;
        int k0 = (idw % 40) * 64, c0 = (idw / 40) * 64;
        #pragma unroll
        for (int i = 0; i < 16; i++) {
            int k_l = i * 4 + hi;
            lds[k_l][lo] = w2[((size_t)k0 + k_l) * C_DIM + c0 + lo];
        }
        __syncthreads();
        #pragma unroll
        for (int i = 0; i < 16; i++) {
            int c_l = i * 4 + hi;
            w2t[((size_t)c0 + c_l) * KG2 + k0 + lo] = f2bf(lds[lo][c_l]);
        }
    }
}

// ========= GEMM1 (BK=128: two k-halves per phase, 64 MFMA/wave per barrier) =========
// Hc[base_a+i][d] = gelu(norm[tok_i] @ w1'[a] + bias1[a]).
__global__ __launch_bounds__(256) void gemm1c(const ushort_t* __restrict__ normG,
                                              const ushort_t* __restrict__ w1t,
                                              const float* __restrict__ bias1,
                                              const int* __restrict__ tokw,
                                              const int* __restrict__ cnt,
                                              ushort_t* __restrict__ Hc) {
    int a = blockIdx.z;
    int mcount = cnt[a];
    int m0 = blockIdx.y * 128;
    if (m0 >= mcount) return;
    int n0 = blockIdx.x * 128;
    int base = 0;
    for (int a2 = 0; a2 < a; a2++) base += cnt[a2];

    __shared__ __align__(16) ushort_t As[2][128 * 64];   // 32 KB (two k-halves)
    __shared__ __align__(16) ushort_t Bs[2][128 * 64];   // 32 KB

    const int tid = threadIdx.x, lane = tid & 63, w = tid >> 6;
    const int wr = w >> 1, wc = w & 1;
    const int lrow = lane & 15, quad = lane >> 4, swzr = lrow & 7;
    const int lrow8 = lane >> 3;
    const int scol = ((lane & 7) ^ lrow8) * 8;
    const int srowl = w * 32 + lrow8;

    const ushort_t* ap[4];
    const ushort_t* bp[4];
    #pragma unroll
    for (int i = 0; i < 4; i++) {
        int rt = tokw[a * NTOK + m0 + srowl + i * 8] & (NTOK - 1);
        ap[i] = normG + (size_t)rt * C_DIM + scol;
        bp[i] = w1t + ((size_t)a * CR + n0 + srowl + i * 8) * C_DIM + scol;
    }

    // hoisted: bias load overlaps the K loop
    float bi[4];
    #pragma unroll
    for (int nt = 0; nt < 4; nt++)
        bi[nt] = bias1[a * CR + n0 + wc * 64 + nt * 16 + lrow];

    f32x4 acc[4][4];
    #pragma unroll
    for (int i = 0; i < 4; i++)
        #pragma unroll
        for (int j = 0; j < 4; j++)
            #pragma unroll
            for (int e = 0; e < 4; e++) acc[i][j][e] = 0.f;

    for (int k0 = 0; k0 < C_DIM; k0 += 128) {
        __syncthreads();                       // prior phase's reads done
        #pragma unroll
        for (int h = 0; h < 2; h++) {
            int kk = k0 + h * 64;
            #pragma unroll
            for (int i = 0; i < 4; i++) {
                __builtin_amdgcn_global_load_lds(
                    (__attribute__((address_space(1))) void*)(ap[i] + kk),
                    (__attribute__((address_space(3))) void*)(&As[h][(w * 32 + i * 8) * 64]),
                    16, 0, 0);
                __builtin_amdgcn_global_load_lds(
                    (__attribute__((address_space(1))) void*)(bp[i] + kk),
                    (__attribute__((address_space(3))) void*)(&Bs[h][(w * 32 + i * 8) * 64]),
                    16, 0, 0);
            }
        }
        __syncthreads();                       // data ready (drains vmcnt once per 128-K)
        #pragma unroll
        for (int h = 0; h < 2; h++)
            #pragma unroll
            for (int ks = 0; ks < 2; ks++) {
                const int cidx = ((ks * 4 + quad) ^ swzr) * 8;
                bf16x8 af[4], bfr[4];
                #pragma unroll
                for (int mt = 0; mt < 4; mt++)
                    af[mt] = *(const bf16x8*)(&As[h][(wr * 64 + mt * 16 + lrow) * 64 + cidx]);
                #pragma unroll
                for (int nt = 0; nt < 4; nt++)
                    bfr[nt] = *(const bf16x8*)(&Bs[h][(wc * 64 + nt * 16 + lrow) * 64 + cidx]);
                #pragma unroll
                for (int mt = 0; mt < 4; mt++)
                    #pragma unroll
                    for (int nt = 0; nt < 4; nt++)
                        acc[mt][nt] = __builtin_amdgcn_mfma_f32_16x16x32_bf16(af[mt], bfr[nt], acc[mt][nt], 0, 0, 0);
            }
    }

    #pragma unroll
    for (int mt = 0; mt < 4; mt++)
        #pragma unroll
        for (int r = 0; r < 4; r++) {
            int i_row = m0 + wr * 64 + mt * 16 + quad * 4 + r;
            bool live = i_row < mcount;
            #pragma unroll
            for (int nt = 0; nt < 4; nt++) {
                int col = n0 + wc * 64 + nt * 16 + lrow;
                float v = acc[mt][nt][r] + bi[nt];
                if (live)
                    Hc[(size_t)(base + i_row) * CR + col] = f2bf(fast_gelu(v));
            }
        }
}

// GEMM2 wide (512 thr, 8 waves 2x4): O[base_a+i][n0..n0+256) = Hc_a[i] @ w2t[a]
// 128x256 tile, K=256. 48 KB LDS -> 3 blocks/CU co-resident.
__global__ __launch_bounds__(512) void gemm2w(const ushort_t* __restrict__ Hc,
                                              const ushort_t* __restrict__ w2t,
                                              const int* __restrict__ cnt,
                                              ushort_t* __restrict__ O) {
    int a = blockIdx.z;
    int mcount = cnt[a];
    int m0 = blockIdx.y * 128;
    if (m0 >= mcount) return;
    int n0 = blockIdx.x * 256;
    int base = 0;
    for (int a2 = 0; a2 < a; a2++) base += cnt[a2];

    __shared__ __align__(16) ushort_t As[128 * 64];   // 16 KB
    __shared__ __align__(16) ushort_t Bs[256 * 64];   // 32 KB

    const int tid = threadIdx.x;
    const int lane = tid & 63, w = tid >> 6;
    const int wr = w >> 2, wc = w & 3;          // 2x4 wave grid
    const int lrow = lane & 15, quad = lane >> 4, swzr = lrow & 7;
    const int srow = tid >> 3;                  // 0..63 staging row within group
    const int slotswz = ((tid & 7) ^ (srow & 7)) * 8;  // pre-swizzled k8 slot

    const ushort_t* ap[2];
    #pragma unroll
    for (int i = 0; i < 2; i++)
        ap[i] = Hc + (size_t)(base + m0 + i * 64 + srow) * CR + slotswz;
    const ushort_t* bp[4];
    #pragma unroll
    for (int i = 0; i < 4; i++)
        bp[i] = w2t + (size_t)(n0 + i * 64 + srow) * KG2 + (size_t)a * CR + slotswz;

    f32x4 acc[4][4];
    #pragma unroll
    for (int i = 0; i < 4; i++)
        #pragma unroll
        for (int j = 0; j < 4; j++)
            #pragma unroll
            for (int e = 0; e < 4; e++) acc[i][j][e] = 0.f;

    for (int k0 = 0; k0 < CR; k0 += 64) {
        __syncthreads();
        #pragma unroll
        for (int i = 0; i < 2; i++)
            __builtin_amdgcn_global_load_lds(
                (__attribute__((address_space(1))) void*)(ap[i] + k0),
                (__attribute__((address_space(3))) void*)(As + i * 4096 + w * 512),
                16, 0, 0);
        #pragma unroll
        for (int i = 0; i < 4; i++)
            __builtin_amdgcn_global_load_lds(
                (__attribute__((address_space(1))) void*)(bp[i] + k0),
                (__attribute__((address_space(3))) void*)(Bs + i * 4096 + w * 512),
                16, 0, 0);
        __syncthreads();
        #pragma unroll
        for (int ks = 0; ks < 2; ks++) {
            const int cidx = ((ks * 4 + quad) ^ swzr) * 8;
            bf16x8 af[4], bfr[4];
            #pragma unroll
            for (int mt = 0; mt < 4; mt++)
                af[mt] = *(const bf16x8*)(As + (wr * 64 + mt * 16 + lrow) * 64 + cidx);
            #pragma unroll
            for (int nt = 0; nt < 4; nt++)
                bfr[nt] = *(const bf16x8*)(Bs + (wc * 64 + nt * 16 + lrow) * 64 + cidx);
            #pragma unroll
            for (int mt = 0; mt < 4; mt++)
                #pragma unroll
                for (int nt = 0; nt < 4; nt++)
                    acc[mt][nt] = __builtin_amdgcn_mfma_f32_16x16x32_bf16(af[mt], bfr[nt], acc[mt][nt], 0, 0, 0);
        }
    }

    #pragma unroll
    for (int mt = 0; mt < 4; mt++)
        #pragma unroll
        for (int r = 0; r < 4; r++) {
            int i_row = m0 + wr * 64 + mt * 16 + quad * 4 + r;
            bool live = i_row < mcount;
            #pragma unroll
            for (int nt = 0; nt < 4; nt++) {
                int col = n0 + wc * 64 + nt * 16 + lrow;
                if (live)
                    O[(size_t)(base + i_row) * C_DIM + col] = f2bf(acc[mt][nt][r]);
            }
        }
}

// final gather v3: out[b][c][p] = feat + sum_j w_j * O[gpos_j(t)][c]
// 64p x 256c tile; uint2 (4xbf16) gathers -> 512 B segments on the random
// O-row reads (half the request count of the 256 B version). f32[64][258]
// staging tile = 66 KB dynamic LDS (2 blocks/CU); pitch 258 words keeps the
// write-phase transposed read at 2-way (free) bank aliasing.
__global__ __launch_bounds__(256) void finalk3(const ushort_t* __restrict__ O,
                                               const int* __restrict__ tokmap,
                                               const int* __restrict__ cnt,
                                               const float* __restrict__ feat,
                                               float* __restrict__ out) {
    extern __shared__ __align__(16) float tile[];   // [64][258]
    __shared__ int pbase[A_N];
    int p0 = blockIdx.x * 64, c0 = blockIdx.y * 256, b = blockIdx.z;
    int tid = threadIdx.x, lo = tid & 63, hi = tid >> 6;
    if (tid < A_N) {
        int s = 0;
        for (int k = 0; k < tid; k++) s += cnt[k];
        pbase[tid] = s;
    }
    __syncthreads();
    #pragma unroll
    for (int i = 0; i < 16; i++) {
        int tl = i * 4 + hi;
        int t = b * HW_N + p0 + tl;
        float v[4] = {0.f, 0.f, 0.f, 0.f};
        #pragma unroll
        for (int j = 0; j < 3; j++) {
            int e = tokmap[t * 3 + j];
            float wv = (float)(e >> 17) * (1.0f / 3.0f);
            int a2 = (e >> 13) & 15;
            int row = pbase[a2] + (e & 8191);
            uint32x2 u = *(const uint32x2*)(O + (size_t)row * C_DIM + c0 + lo * 4);
            v[0] += wv * bf2f((ushort_t)(u[0] & 0xffffu));
            v[1] += wv * bf2f((ushort_t)(u[0] >> 16));
            v[2] += wv * bf2f((ushort_t)(u[1] & 0xffffu));
            v[3] += wv * bf2f((ushort_t)(u[1] >> 16));
        }
        #pragma unroll
        for (int k = 0; k < 4; k++)
            tile[tl * 258 + lo * 4 + k] = v[k];
    }
    __syncthreads();
    #pragma unroll
    for (int i = 0; i < 64; i++) {
        int c_l = i * 4 + hi;
        size_t o = ((size_t)b * C_DIM + c0 + c_l) * HW_N + p0 + lo;
        out[o] = tile[lo * 258 + c_l] + feat[o];
    }
}

// ---------------- launch ----------------
extern "C" void kernel_launch(void* const* d_in, const int* in_sizes, int n_in,
                              void* d_out, int out_size, void* d_ws, size_t ws_size,
                              hipStream_t stream) {
    (void)in_sizes; (void)n_in; (void)out_size; (void)ws_size;
    const float* feat = (const float*)d_in[0];
    const float* ar   = (const float*)d_in[1];
    const float* ln_s = (const float*)d_in[2];
    const float* ln_b = (const float*)d_in[3];
    const float* w1   = (const float*)d_in[4];
    const float* w2   = (const float*)d_in[5];
    float* out = (float*)d_out;
    char* ws = (char*)d_ws;

    // allow >64 KB dynamic LDS for finalk3's staging tile
    (void)hipFuncSetAttribute((const void*)finalk3,
                              hipFuncAttributeMaxDynamicSharedMemorySize,
                              FIN_LDS);

    // ---- zero-init region (atomic targets only: bias1 + cnt) ----
    float*    bias1  = (float*)(ws + 0);          // 10,240
    int*      cnt    = (int*)(ws + 10240);        // 40 (pad to 10,496)
    const size_t ZERO_BYTES = 10496;
    // ---- uninitialized region ----
    int*      tokmap = (int*)(ws + 10496);        // 98,304   -> 108,800
    int*      tokw   = (int*)(ws + 108800);       // 327,680  -> 436,480
    ushort_t* w1t    = (ushort_t*)(ws + 436480);  // 5,242,880 -> 5,679,360
    ushort_t* w2t    = (ushort_t*)(ws + 5679360); // 5,242,880 -> 10,922,240
    ushort_t* normG  = (ushort_t*)(ws + 10922240);// 16,777,216 -> 27,699,456
    ushort_t* Hc     = (ushort_t*)(ws + 27699456);// (24576+128)*256*2 = 12,648,448 -> 40,347,904
    ushort_t* O      = (ushort_t*)(ws + 40347904);// 24576*1024*2 = 50,331,648 -> 90,679,552

    dim3 blk(256);
    hipMemsetAsync(ws, 0, ZERO_BYTES, stream);
    prep_all<<<dim3(1568), blk, 0, stream>>>(w1, w2, ln_s, ln_b, feat, ar,
                                             w1t, w2t, bias1, cnt, tokw, tokmap, normG);
    gemm1c<<<dim3(2, 64, A_N), blk, 0, stream>>>(normG, w1t, bias1, tokw, cnt, Hc);
    gemm2w<<<dim3(4, 64, A_N), dim3(512), 0, stream>>>(Hc, w2t, cnt, O);
    finalk3<<<dim3(64, 4, B_N), blk, FIN_LDS, stream>>>(O, tokmap, cnt, feat, out);
}